// Round 1
// baseline (562.721 us; speedup 1.0000x reference)
//
#include <hip/hip_runtime.h>

// Problem constants (from reference)
#define BQ 2048        // queries
#define NS 32768       // support points
#define DIM 256        // embedding dim
#define BM 64          // query tile per block
#define BN 64          // support tile per inner iteration
#define BK 16          // k-tile staged per step
#define NCHUNK 2048    // support range per block (grid.y)
#define NCHUNKS (NS / NCHUNK)  // 16

// ---------------------------------------------------------------------------
// Kernel 1: s2[n] = ||support[n]||^2.  One wave per row (64 lanes x float4).
// ---------------------------------------------------------------------------
__global__ __launch_bounds__(256) void s2_kernel(const float* __restrict__ s,
                                                 float* __restrict__ s2) {
    int wave = threadIdx.x >> 6;
    int lane = threadIdx.x & 63;
    int row  = blockIdx.x * 4 + wave;
    const float4* p = (const float4*)(s + (size_t)row * DIM);
    float4 v = p[lane];
    float sum = v.x * v.x + v.y * v.y + v.z * v.z + v.w * v.w;
#pragma unroll
    for (int off = 32; off > 0; off >>= 1)
        sum += __shfl_xor(sum, off);
    if (lane == 0) s2[row] = sum;
}

// ---------------------------------------------------------------------------
// Kernel 2: fused GEMM + running argmin.
// Block: 256 threads, BM=64 queries x NCHUNK=2048 supports.
// X tile (64 x 256 fp32, k-major) resident in LDS for whole block (64 KB).
// Support staged BN=64 x BK=16 per step (4 KB). 4x4 register micro-tile.
// Score = s2[n] - 2*dot(x,s)  (monotone in the reference distance).
// ---------------------------------------------------------------------------
__global__ __launch_bounds__(256) void knn_main(const float* __restrict__ x,
                                                const float* __restrict__ sup,
                                                const float* __restrict__ s2g,
                                                float* __restrict__ pvals,
                                                int* __restrict__ pidx) {
    __shared__ float Xs[DIM][BM];   // 64 KB, Xs[k][m]
    __shared__ float Bs[BK][BN];    // 4 KB,  Bs[k][n]

    const int tid = threadIdx.x;
    const int tx  = tid & 15;       // support sub-tile (cols 4*tx..4*tx+3)
    const int ty  = tid >> 4;       // query sub-tile  (rows 4*ty..4*ty+3)
    const int m0    = blockIdx.x * BM;
    const int nbase = blockIdx.y * NCHUNK;

    // ---- Load X tile once: thread -> row tid/4, float4 column (tid%4)*4 ----
    {
        const int mrow = tid >> 2;          // 0..63
        const int kq   = (tid & 3) * 4;     // 0,4,8,12
        const float* xr = x + (size_t)(m0 + mrow) * DIM;
#pragma unroll
        for (int kk = 0; kk < 16; ++kk) {
            float4 v = *(const float4*)(xr + kk * 16 + kq);
            Xs[kk * 16 + kq + 0][mrow] = v.x;
            Xs[kk * 16 + kq + 1][mrow] = v.y;
            Xs[kk * 16 + kq + 2][mrow] = v.z;
            Xs[kk * 16 + kq + 3][mrow] = v.w;
        }
    }
    __syncthreads();

    float rmin[4];
    int   ridx[4];
#pragma unroll
    for (int i = 0; i < 4; ++i) { rmin[i] = 3.4e38f; ridx[i] = 0; }

    const int srow = tid >> 2;          // support row within tile
    const int skq  = (tid & 3) * 4;     // k offset within BK

    for (int nt = 0; nt < NCHUNK / BN; ++nt) {
        const int n0 = nbase + nt * BN;

        float acc[4][4];
#pragma unroll
        for (int i = 0; i < 4; ++i)
#pragma unroll
            for (int j = 0; j < 4; ++j) acc[i][j] = 0.0f;

        for (int kk = 0; kk < DIM / BK; ++kk) {
            // issue global load before the barrier (register destination)
            float4 v = *(const float4*)(sup + (size_t)(n0 + srow) * DIM + kk * BK + skq);
            __syncthreads();            // prior inner-loop reads of Bs done
            Bs[skq + 0][srow] = v.x;
            Bs[skq + 1][srow] = v.y;
            Bs[skq + 2][srow] = v.z;
            Bs[skq + 3][srow] = v.w;
            __syncthreads();

#pragma unroll
            for (int k = 0; k < BK; ++k) {
                float4 a = *(const float4*)&Xs[kk * BK + k][ty * 4];
                float4 b = *(const float4*)&Bs[k][tx * 4];
                acc[0][0] = fmaf(a.x, b.x, acc[0][0]);
                acc[0][1] = fmaf(a.x, b.y, acc[0][1]);
                acc[0][2] = fmaf(a.x, b.z, acc[0][2]);
                acc[0][3] = fmaf(a.x, b.w, acc[0][3]);
                acc[1][0] = fmaf(a.y, b.x, acc[1][0]);
                acc[1][1] = fmaf(a.y, b.y, acc[1][1]);
                acc[1][2] = fmaf(a.y, b.z, acc[1][2]);
                acc[1][3] = fmaf(a.y, b.w, acc[1][3]);
                acc[2][0] = fmaf(a.z, b.x, acc[2][0]);
                acc[2][1] = fmaf(a.z, b.y, acc[2][1]);
                acc[2][2] = fmaf(a.z, b.z, acc[2][2]);
                acc[2][3] = fmaf(a.z, b.w, acc[2][3]);
                acc[3][0] = fmaf(a.w, b.x, acc[3][0]);
                acc[3][1] = fmaf(a.w, b.y, acc[3][1]);
                acc[3][2] = fmaf(a.w, b.z, acc[3][2]);
                acc[3][3] = fmaf(a.w, b.w, acc[3][3]);
            }
        }

        // ---- fused argmin epilogue for this BN tile ----
        const int nb = n0 + tx * 4;
        float4 s2v = *(const float4*)(s2g + nb);
        float s2a[4] = { s2v.x, s2v.y, s2v.z, s2v.w };
#pragma unroll
        for (int i = 0; i < 4; ++i) {
#pragma unroll
            for (int j = 0; j < 4; ++j) {
                float sc = s2a[j] - 2.0f * acc[i][j];
                // strict '<' in ascending-index scan order keeps earliest index
                if (sc < rmin[i]) { rmin[i] = sc; ridx[i] = nb + j; }
            }
        }
    }

    // ---- block-level reduce across the 16 tx lanes per query row ----
    __syncthreads();                      // everyone done reading Xs
    float* sv = &Xs[0][0];                // reuse LDS: 64x16 floats (4 KB)
    int*   si = (int*)(sv + 64 * 16);     // next 4 KB
#pragma unroll
    for (int i = 0; i < 4; ++i) {
        sv[(ty * 4 + i) * 16 + tx] = rmin[i];
        si[(ty * 4 + i) * 16 + tx] = ridx[i];
    }
    __syncthreads();
    if (tid < 64) {
        float best = sv[tid * 16];
        int   bi   = si[tid * 16];
#pragma unroll
        for (int t = 1; t < 16; ++t) {
            float v = sv[tid * 16 + t];
            int   ix = si[tid * 16 + t];
            if (v < best || (v == best && ix < bi)) { best = v; bi = ix; }
        }
        const int bglob = m0 + tid;
        pvals[bglob * NCHUNKS + blockIdx.y] = best;
        pidx [bglob * NCHUNKS + blockIdx.y] = bi;
    }
}

// ---------------------------------------------------------------------------
// Kernel 3: per-query reduce over NCHUNKS partials, label gather, one-hot.
// Detects int64-vs-int32 label storage at runtime (odd int32 words all zero
// => int64 little-endian layout; labels are in [0,100)).
// ---------------------------------------------------------------------------
__global__ __launch_bounds__(128) void finalize_kernel(const float* __restrict__ pvals,
                                                       const int* __restrict__ pidx,
                                                       const int* __restrict__ labels,
                                                       const int* __restrict__ ncp,
                                                       int* __restrict__ out) {
    const int b   = blockIdx.x;
    const int tid = threadIdx.x;
    __shared__ int s_label;

    if (tid < 64) {
        float v  = 3.4e38f;
        int   ix = 0x7fffffff;
        if (tid < NCHUNKS) {
            v  = pvals[b * NCHUNKS + tid];
            ix = pidx [b * NCHUNKS + tid];
        }
#pragma unroll
        for (int off = 8; off > 0; off >>= 1) {
            float ov = __shfl_down(v, off);
            int   oi = __shfl_down(ix, off);
            if (ov < v || (ov == v && oi < ix)) { v = ov; ix = oi; }
        }
        if (tid == 0) {
            bool is64 = true;
            for (int i = 1; i < 128; i += 2)
                if (labels[i] != 0) { is64 = false; break; }
            s_label = is64 ? labels[2 * ix] : labels[ix];
        }
    }
    __syncthreads();
    const int nc = ncp[0];
    for (int c = tid; c < nc; c += blockDim.x)
        out[b * nc + c] = (c == s_label) ? 1 : 0;
}

// ---------------------------------------------------------------------------
extern "C" void kernel_launch(void* const* d_in, const int* in_sizes, int n_in,
                              void* d_out, int out_size, void* d_ws, size_t ws_size,
                              hipStream_t stream) {
    const float* x      = (const float*)d_in[0];
    const float* sup    = (const float*)d_in[1];
    const int*   labels = (const int*)d_in[2];
    const int*   ncp    = (const int*)d_in[3];
    int* out = (int*)d_out;

    float* s2    = (float*)d_ws;                    // 32768 floats (128 KB)
    float* pvals = s2 + NS;                         // 2048*16 floats (128 KB)
    int*   pidx  = (int*)(pvals + BQ * NCHUNKS);    // 2048*16 ints  (128 KB)

    s2_kernel<<<NS / 4, 256, 0, stream>>>(sup, s2);

    dim3 grid(BQ / BM, NCHUNKS);
    knn_main<<<grid, 256, 0, stream>>>(x, sup, s2, pvals, pidx);

    finalize_kernel<<<BQ, 128, 0, stream>>>(pvals, pidx, labels, ncp, out);
}